// Round 12
// baseline (430.318 us; speedup 1.0000x reference)
//
#include <hip/hip_runtime.h>
#include <stdint.h>

#define N_NODES 100000
#define N_EDGES 1600000
#define NBLK_SCAN 391   // ceil(N_NODES/256)

typedef __attribute__((ext_vector_type(8))) short short8;
typedef __attribute__((ext_vector_type(4))) float float4v;

__device__ __forceinline__ unsigned short f32_to_bf16(float f) {
  uint32_t u = __float_as_uint(f);
  u += 0x7fffu + ((u >> 16) & 1u);   // RNE
  return (unsigned short)(u >> 16);
}

// ---------------------------------------------------------------------------
// K_zero: deg=0; build wbf = 52 MFMA A-fragment tiles (A = W^T):
//   tiles 0..49 : A[row=fo_local][k=fin] = weight[km=t>>1][fin][(t&1)*16+row]
//   tiles 50,51 : root_w^T
// slot((t,q,row,j)) = t*512 + q*128 + row*8 + j,  fin = q*8+j.
// ---------------------------------------------------------------------------
__global__ __launch_bounds__(256) void k_zero(
    const float* __restrict__ weight, const float* __restrict__ root_w,
    int* __restrict__ deg, unsigned short* __restrict__ wbf) {
  int tid = threadIdx.x;
  int b = blockIdx.x;
  int i = b * 256 + tid;
  if (i < N_NODES) deg[i] = 0;
  if (b < 100) {            // 25600 weight-tile slots
    int e = i;
    int t = e >> 9, rem = e & 511;
    int q = rem >> 7, row = (rem >> 3) & 15, j = rem & 7;
    int km = t >> 1, fin = q * 8 + j, fo = (t & 1) * 16 + row;
    wbf[e] = f32_to_bf16(weight[(km * 32 + fin) * 32 + fo]);
  } else if (b == 100) {    // root tiles 50,51
    for (int idx = tid; idx < 1024; idx += 256) {
      int t = 50 + (idx >> 9), rem = idx & 511;
      int q = rem >> 7, row = (rem >> 3) & 15, j = rem & 7;
      int fin = q * 8 + j, fo = (t - 50) * 16 + row;
      wbf[t * 512 + rem] = f32_to_bf16(root_w[fin * 32 + fo]);
    }
  }
}

// ---------------------------------------------------------------------------
// K1_lite (6250 blocks, 16 nodes each): xw is GONE (the 160MB write +
// 308MB re-read was 77% of HBM traffic, both kernels pinned at their
// achieved-BW ceilings across 5 variants). Now:
//  - hist: rank[e] = atomicAdd(&deg[ei[e]],1)
//  - all waves build the x^T B-fragment (lane c16 = node, quad slices fin)
//  - wave 0: stores it as xb (bf16, 6.4MB) — k2_fused's gather source
//  - wave 3: root tiles 50,51 -> out = x_root + bias; r_dot -> od[].y
// ---------------------------------------------------------------------------
__global__ __launch_bounds__(256) void k1_lite(
    const float* __restrict__ x, const unsigned short* __restrict__ wbf,
    const int* __restrict__ ei, const float* __restrict__ att_w,
    const float* __restrict__ bias,
    int* __restrict__ deg, unsigned short* __restrict__ rank,
    unsigned short* __restrict__ xb, float* __restrict__ out,
    uint2* __restrict__ od) {
  int tid = threadIdx.x;
  int b = blockIdx.x;

  int e = b * 256 + tid;
  int rk = atomicAdd(&deg[ei[e]], 1);

  int wave = tid >> 6, lane = tid & 63;
  int quad = lane >> 4, c16 = lane & 15;
  int node = b * 16 + c16;
  const float* xp = x + (size_t)node * 32 + quad * 8;
  float4 a0 = *reinterpret_cast<const float4*>(xp);
  float4 a1 = *reinterpret_cast<const float4*>(xp + 4);
  short8 af;
  af[0] = (short)f32_to_bf16(a0.x); af[1] = (short)f32_to_bf16(a0.y);
  af[2] = (short)f32_to_bf16(a0.z); af[3] = (short)f32_to_bf16(a0.w);
  af[4] = (short)f32_to_bf16(a1.x); af[5] = (short)f32_to_bf16(a1.y);
  af[6] = (short)f32_to_bf16(a1.z); af[7] = (short)f32_to_bf16(a1.w);

  if (wave == 0) {   // persist bf16 x (lane's 16B is contiguous)
    *reinterpret_cast<short8*>(xb + (size_t)node * 32 + quad * 8) = af;
  }
  if (wave == 3) {   // root tiles -> out, r_dot
    float rsum = 0.f;
#pragma unroll
    for (int t = 50; t <= 51; t++) {
      short8 bf = *reinterpret_cast<const short8*>(wbf + ((t * 4 + quad) * 16 + c16) * 8);
      float4v acc = {0.f, 0.f, 0.f, 0.f};
      acc = __builtin_amdgcn_mfma_f32_16x16x32_bf16(bf, af, acc, 0, 0, 0);
      int gfo = (t - 50) * 16 + quad * 4;
      float4 bi = *reinterpret_cast<const float4*>(bias + gfo);
      float4 o;
      o.x = acc[0] + bi.x; o.y = acc[1] + bi.y;
      o.z = acc[2] + bi.z; o.w = acc[3] + bi.w;
      *reinterpret_cast<float4*>(out + (size_t)node * 32 + gfo) = o;
      float4 aw = *reinterpret_cast<const float4*>(att_w + gfo);
      rsum += acc[0] * aw.x + acc[1] * aw.y + acc[2] * aw.z + acc[3] * aw.w;
    }
    rsum += __shfl_xor(rsum, 16);
    rsum += __shfl_xor(rsum, 32);
    if (lane < 16) od[node].y = __float_as_uint(rsum);
  }
  rank[e] = (unsigned short)rk;
}

// ---------------------------------------------------------------------------
// 3-kernel exclusive scan of deg -> offs / od[].x.
// ---------------------------------------------------------------------------
__global__ __launch_bounds__(256) void kscan1(const int* __restrict__ deg,
                                              int* __restrict__ incl,
                                              int* __restrict__ bsum) {
  __shared__ int s[256];
  int tid = threadIdx.x;
  int i = blockIdx.x * 256 + tid;
  int v = (i < N_NODES) ? deg[i] : 0;
  s[tid] = v;
  __syncthreads();
  for (int d = 1; d < 256; d <<= 1) {
    int t = (tid >= d) ? s[tid - d] : 0;
    __syncthreads();
    s[tid] += t;
    __syncthreads();
  }
  if (i < N_NODES) incl[i] = s[tid];
  if (tid == 255) bsum[blockIdx.x] = s[255];
}

__global__ __launch_bounds__(512) void kscan2(const int* __restrict__ bsum,
                                              int* __restrict__ bbase) {
  __shared__ int s[512];
  int tid = threadIdx.x;
  int v = (tid < NBLK_SCAN) ? bsum[tid] : 0;
  s[tid] = v;
  __syncthreads();
  for (int d = 1; d < 512; d <<= 1) {
    int t = (tid >= d) ? s[tid - d] : 0;
    __syncthreads();
    s[tid] += t;
    __syncthreads();
  }
  if (tid < NBLK_SCAN) bbase[tid] = s[tid] - v;  // exclusive
}

__global__ __launch_bounds__(256) void kscan3(const int* __restrict__ deg,
                                              int* __restrict__ offs,
                                              const int* __restrict__ bbase,
                                              uint2* __restrict__ od) {
  int i = blockIdx.x * 256 + threadIdx.x;
  if (i < N_NODES) {
    int v = offs[i] - deg[i] + bbase[i >> 8];
    offs[i] = v;
    od[i].x = (unsigned int)v;
  }
  if (i == 0) {
    offs[N_NODES] = N_EDGES;
    od[N_NODES].x = (unsigned int)N_EDGES;
  }
}

// ---------------------------------------------------------------------------
// K_scatter: 1 edge/thread, 6250 blocks — pos = offs[row] + rank[e].
//   epack.x = col(17b) | w0(5b)      (w0 = i0 + 5*i1)
//   epack.y = fr0_q16 | fr1_q16<<16
// ---------------------------------------------------------------------------
__global__ __launch_bounds__(256) void kscatter(
    const int* __restrict__ ei, const float* __restrict__ pseudo,
    const uint2* __restrict__ od, const unsigned short* __restrict__ rank,
    uint2* __restrict__ epack) {
  int e = blockIdx.x * 256 + threadIdx.x;
  int r = ei[e];
  int c = ei[N_EDGES + e];
  float p0 = pseudo[2 * e] * 4.f;
  float p1 = pseudo[2 * e + 1] * 4.f;
  int rk = rank[e];
  unsigned int offr = od[r].x;
  float fl0 = floorf(p0), fl1 = floorf(p1);
  float fr0 = p0 - fl0, fr1 = p1 - fl1;
  int i0 = (int)fl0, i1 = (int)fl1;
  int w0 = i0 + 5 * i1;
  unsigned int q0 = (unsigned int)(fr0 * 65535.f + 0.5f);
  unsigned int q1 = (unsigned int)(fr1 * 65535.f + 0.5f);
  uint2 pk;
  pk.x = (unsigned int)c | ((unsigned int)w0 << 17);
  pk.y = q0 | (q1 << 16);
  epack[offr + rk] = pk;
}

// ---------------------------------------------------------------------------
// K2_fused (12500 blocks x 512 thr = 8 waves; wave = node): computes edge
// messages BY MFMA instead of gathering precomputed xw.
//  - block stages the 50 W-tiles (51.2 KB) in LDS once.
//  - per chunk of 16 edges: lane(quad,c16) gathers xb[col_{c16}] 16B as the
//    B-fragment (same layout as k1's af — proven); for each w in 0..24 the
//    A-fragment pair (fo 0-15 / 16-31) comes from LDS, 2 MFMAs give
//    D[fo][edge], and msg[e][fo] += cf_e(w) * D (cf = edge's bilinear coef
//    for w: nonzero only for w in {w0,w0+1,w0+5,w0+6}; __any skips unused w).
//  - softmax: lane holds 8 fo's of ONE edge -> alpha partial, 2 shuffles
//    (xor 16,32) across quads; ex masked by chunk validity; acc/den.
//  - final: reduce acc/den across the 16 edge-lanes (xor 1,2,4,8), lanes
//    c16==0 do the out read-modify-write (out holds x_root + bias).
// ---------------------------------------------------------------------------
__global__ __launch_bounds__(512) void k2_fused(
    const uint2* __restrict__ od, const uint2* __restrict__ epack,
    const unsigned short* __restrict__ xb, const unsigned short* __restrict__ wbf,
    const float* __restrict__ att_w, float* __restrict__ out) {
  __shared__ __align__(16) unsigned short lw[25600];   // 50 tiles, 51.2 KB
  int tid = threadIdx.x;
  // stage W tiles
  {
    const uint4* src = reinterpret_cast<const uint4*>(wbf);
    uint4* dst = reinterpret_cast<uint4*>(lw);
    for (int j = tid; j < 3200; j += 512) dst[j] = src[j];
  }
  __syncthreads();

  int wave = tid >> 6, lane = tid & 63;
  int quad = lane >> 4, c16 = lane & 15;
  int node = blockIdx.x * 8 + wave;
  uint2 v0 = od[node];
  int s0 = (int)v0.x;
  int s1 = (int)od[node + 1].x;
  float rd = __uint_as_float(v0.y);

  float aw0[4], aw1[4];
#pragma unroll
  for (int r = 0; r < 4; r++) {
    aw0[r] = att_w[32 + quad * 4 + r];
    aw1[r] = att_w[48 + quad * 4 + r];
  }

  float acc0[4] = {0.f, 0.f, 0.f, 0.f};
  float acc1[4] = {0.f, 0.f, 0.f, 0.f};
  float den = 0.f;
  const float Q = 1.f / 65535.f;

  for (int base = s0; base < s1; base += 16) {
    int m2 = s1 - base; if (m2 > 16) m2 = 16;
    int valid = (c16 < m2);
    uint2 ep = epack[base + (valid ? c16 : 0)];
    int col = (int)(ep.x & 0x1FFFF);
    int w0 = (int)(ep.x >> 17);
    float fr0 = (float)(ep.y & 0xffff) * Q;
    float fr1 = (float)(ep.y >> 16) * Q;
    float b0 = (1.f - fr0) * (1.f - fr1);
    float b1 = fr0 * (1.f - fr1);
    float b2 = (1.f - fr0) * fr1;
    float b3 = fr0 * fr1;
    // B-fragment: lane (quad,c16) = xb[col][quad*8 .. +8)
    short8 bx = *reinterpret_cast<const short8*>(xb + (size_t)col * 32 + quad * 8);

    float m0[4] = {0.f, 0.f, 0.f, 0.f};
    float m1[4] = {0.f, 0.f, 0.f, 0.f};
#pragma unroll
    for (int w = 0; w < 25; w++) {
      int dw = w - w0;
      float cf = (dw == 0) ? b0 : (dw == 1) ? b1 : (dw == 5) ? b2
                 : (dw == 6) ? b3 : 0.f;
      if (__any(cf != 0.f)) {
        short8 a0 = *reinterpret_cast<const short8*>(lw + (2 * w) * 512 + quad * 128 + c16 * 8);
        short8 a1 = *reinterpret_cast<const short8*>(lw + (2 * w + 1) * 512 + quad * 128 + c16 * 8);
        float4v z0 = {0.f, 0.f, 0.f, 0.f};
        float4v z1 = {0.f, 0.f, 0.f, 0.f};
        z0 = __builtin_amdgcn_mfma_f32_16x16x32_bf16(a0, bx, z0, 0, 0, 0);
        z1 = __builtin_amdgcn_mfma_f32_16x16x32_bf16(a1, bx, z1, 0, 0, 0);
#pragma unroll
        for (int r = 0; r < 4; r++) {
          m0[r] += cf * z0[r];
          m1[r] += cf * z1[r];
        }
      }
    }
    // alpha for this lane's edge
    float p = 0.f;
#pragma unroll
    for (int r = 0; r < 4; r++) p += m0[r] * aw0[r] + m1[r] * aw1[r];
    p += __shfl_xor(p, 16);
    p += __shfl_xor(p, 32);
    float alpha = rd + p;
    alpha = alpha > 0.f ? alpha : 0.2f * alpha;
    float ex = valid ? __expf(alpha) : 0.f;
    den += ex;
#pragma unroll
    for (int r = 0; r < 4; r++) {
      acc0[r] += ex * m0[r];
      acc1[r] += ex * m1[r];
    }
  }

  // reduce across the 16 edge-lanes (lane bits 0..3)
#pragma unroll
  for (int msk = 1; msk <= 8; msk <<= 1) {
    den += __shfl_xor(den, msk);
#pragma unroll
    for (int r = 0; r < 4; r++) {
      acc0[r] += __shfl_xor(acc0[r], msk);
      acc1[r] += __shfl_xor(acc1[r], msk);
    }
  }
  if (c16 == 0) {
    float inv = 1.f / (den + 1e-16f);
    float* op = out + (size_t)node * 32 + quad * 4;
    float4 o0 = *reinterpret_cast<const float4*>(op);
    o0.x += acc0[0] * inv; o0.y += acc0[1] * inv;
    o0.z += acc0[2] * inv; o0.w += acc0[3] * inv;
    *reinterpret_cast<float4*>(op) = o0;
    float* op1 = op + 16;
    float4 o1 = *reinterpret_cast<const float4*>(op1);
    o1.x += acc1[0] * inv; o1.y += acc1[1] * inv;
    o1.z += acc1[2] * inv; o1.w += acc1[3] * inv;
    *reinterpret_cast<float4*>(op1) = o1;
  }
}

extern "C" void kernel_launch(void* const* d_in, const int* in_sizes, int n_in,
                              void* d_out, int out_size, void* d_ws, size_t ws_size,
                              hipStream_t stream) {
  const float* x      = (const float*)d_in[0];
  const int*   ei     = (const int*)d_in[1];
  const float* pseudo = (const float*)d_in[2];
  const float* weight = (const float*)d_in[3];
  const float* root_w = (const float*)d_in[4];
  const float* att_w  = (const float*)d_in[5];
  const float* bias   = (const float*)d_in[6];
  float* out = (float*)d_out;

  char* ws = (char*)d_ws;
  unsigned short* xb   = (unsigned short*)ws;                 //   6,400,000 B
  uint2* od            = (uint2*)(ws + 6400000);              //     800,016 B
  unsigned short* wbf  = (unsigned short*)(ws + 7200016);     //      53,248 B
  int* deg             = (int*)(ws + 7253264);                //     400,000 B
  int* offs            = (int*)(ws + 7653264);                //     400,016 B
  int* bsum            = (int*)(ws + 8053280);                //       1,600 B
  int* bbase           = (int*)(ws + 8054880);                //       1,600 B
  unsigned short* rank = (unsigned short*)(ws + 8056480);     //   3,200,000 B
  uint2* epack         = (uint2*)(ws + 11256480);             //  12,800,000 B -> 24.06 MB

  hipLaunchKernelGGL(k_zero, dim3(NBLK_SCAN), dim3(256), 0, stream,
                     weight, root_w, deg, wbf);
  hipLaunchKernelGGL(k1_lite, dim3(6250), dim3(256), 0, stream,
                     x, wbf, ei, att_w, bias, deg, rank, xb, out, od);
  hipLaunchKernelGGL(kscan1, dim3(NBLK_SCAN), dim3(256), 0, stream, deg, offs, bsum);
  hipLaunchKernelGGL(kscan2, dim3(1), dim3(512), 0, stream, bsum, bbase);
  hipLaunchKernelGGL(kscan3, dim3(NBLK_SCAN), dim3(256), 0, stream,
                     deg, offs, bbase, od);
  hipLaunchKernelGGL(kscatter, dim3(6250), dim3(256), 0, stream,
                     ei, pseudo, od, rank, epack);
  hipLaunchKernelGGL(k2_fused, dim3(12500), dim3(512), 0, stream,
                     od, epack, xb, wbf, att_w, out);
}

// Round 13
// 329.451 us; speedup vs baseline: 1.3062x; 1.3062x over previous
//
#include <hip/hip_runtime.h>
#include <stdint.h>

#define N_NODES 100000
#define N_EDGES 1600000
#define NBLK_SCAN 391   // ceil(N_NODES/256)

typedef __attribute__((ext_vector_type(8))) short short8;
typedef __attribute__((ext_vector_type(4))) float float4v;

__device__ __forceinline__ unsigned short f32_to_bf16(float f) {
  uint32_t u = __float_as_uint(f);
  u += 0x7fffu + ((u >> 16) & 1u);   // RNE
  return (unsigned short)(u >> 16);
}
__device__ __forceinline__ float bf16_to_f32(unsigned short h) {
  return __uint_as_float(((uint32_t)h) << 16);
}

// ---------------------------------------------------------------------------
// K_zero: deg=0; build wbf = 52 MFMA A-fragment tiles (A = W^T):
//   tiles 0..49 : A[row=fo_local][k=fin] = weight[km=t>>1][fin][(t&1)*16+row]
//   tiles 50,51 : root_w^T
// slot((t,q,row,j)) = t*512 + q*128 + row*8 + j,  fin = q*8+j.
// ---------------------------------------------------------------------------
__global__ __launch_bounds__(256) void k_zero(
    const float* __restrict__ weight, const float* __restrict__ root_w,
    int* __restrict__ deg, unsigned short* __restrict__ wbf) {
  int tid = threadIdx.x;
  int b = blockIdx.x;
  int i = b * 256 + tid;
  if (i < N_NODES) deg[i] = 0;
  if (b < 100) {            // 25600 weight-tile slots
    int e = i;
    int t = e >> 9, rem = e & 511;
    int q = rem >> 7, row = (rem >> 3) & 15, j = rem & 7;
    int km = t >> 1, fin = q * 8 + j, fo = (t & 1) * 16 + row;
    wbf[e] = f32_to_bf16(weight[(km * 32 + fin) * 32 + fo]);
  } else if (b == 100) {    // root tiles 50,51
    for (int idx = tid; idx < 1024; idx += 256) {
      int t = 50 + (idx >> 9), rem = idx & 511;
      int q = rem >> 7, row = (rem >> 3) & 15, j = rem & 7;
      int fin = q * 8 + j, fo = (t - 50) * 16 + row;
      wbf[t * 512 + rem] = f32_to_bf16(root_w[fin * 32 + fo]);
    }
  }
}

// ---------------------------------------------------------------------------
// K1 (6250 blocks, 16 nodes each) — round-10 structure (322us best), ONE
// change: copy-out widened to uint4 (16B) stores — tests whether k1's
// 2.2 TB/s write rate (70% of the ~3.15 TB/s write-path share, 5 variants
// pinned at 104-111us) is store-burst/issue-limited (a) or a hard
// write-path+atomic-churn ceiling (b).
//  - hist: rank[e] = atomicAdd(&deg[ei[e]],1), stored at the end.
//  - 52 tiles = 4 waves x 13: uniform loop.
//  - D[fo][node]: lane packs 4 features of one node as uint2, staged at
//    swizzled LDS slot tq*16 + (c16 ^ (tq&15)).
//  - tiles 50,51 (wave 3): out = x_root + bias; r_dot -> od[].y
// ---------------------------------------------------------------------------
__global__ __launch_bounds__(256) void k1_xw(
    const float* __restrict__ x, const unsigned short* __restrict__ wbf,
    const int* __restrict__ ei, const float* __restrict__ att_w,
    const float* __restrict__ bias,
    int* __restrict__ deg, unsigned short* __restrict__ rank,
    unsigned short* __restrict__ xw, float* __restrict__ out,
    uint2* __restrict__ od) {
  __shared__ __align__(16) uint2 st[3200];   // 25.6 KB: tiles 0..49
  int tid = threadIdx.x;
  int b = blockIdx.x;

  int e = b * 256 + tid;
  int rk = atomicAdd(&deg[ei[e]], 1);

  int wave = tid >> 6, lane = tid & 63;
  int quad = lane >> 4, c16 = lane & 15;
  int n0 = b * 16;
  int node = n0 + c16;
  // B-fragment = x^T: lane holds x[node=c16][fin = quad*8 + j]
  const float* xp = x + (size_t)node * 32 + quad * 8;
  float4 a0 = *reinterpret_cast<const float4*>(xp);
  float4 a1 = *reinterpret_cast<const float4*>(xp + 4);
  short8 af;
  af[0] = (short)f32_to_bf16(a0.x); af[1] = (short)f32_to_bf16(a0.y);
  af[2] = (short)f32_to_bf16(a0.z); af[3] = (short)f32_to_bf16(a0.w);
  af[4] = (short)f32_to_bf16(a1.x); af[5] = (short)f32_to_bf16(a1.y);
  af[6] = (short)f32_to_bf16(a1.z); af[7] = (short)f32_to_bf16(a1.w);

  float rsum = 0.f;
  for (int idx = 0; idx < 13; idx++) {
    int t = wave * 13 + idx;
    // A-fragment: lane holds A[row=c16][k=quad*8+j]
    short8 bf = *reinterpret_cast<const short8*>(wbf + ((t * 4 + quad) * 16 + c16) * 8);
    float4v acc = {0.f, 0.f, 0.f, 0.f};
    acc = __builtin_amdgcn_mfma_f32_16x16x32_bf16(bf, af, acc, 0, 0, 0);
    // D: col=lane&15=node, row=quad*4+r = fo_local
    if (t < 50) {
      uint2 pk;
      pk.x = (unsigned int)f32_to_bf16(acc[0]) |
             ((unsigned int)f32_to_bf16(acc[1]) << 16);
      pk.y = (unsigned int)f32_to_bf16(acc[2]) |
             ((unsigned int)f32_to_bf16(acc[3]) << 16);
      int tq = t * 4 + quad;
      st[tq * 16 + (c16 ^ (tq & 15))] = pk;
    } else {               // wave 3 only: tiles 50,51
      int gfo = (t - 50) * 16 + quad * 4;
      float4 bi = *reinterpret_cast<const float4*>(bias + gfo);
      float4 o;
      o.x = acc[0] + bi.x; o.y = acc[1] + bi.y;
      o.z = acc[2] + bi.z; o.w = acc[3] + bi.w;
      *reinterpret_cast<float4*>(out + (size_t)node * 32 + gfo) = o;
      float4 aw = *reinterpret_cast<const float4*>(att_w + gfo);
      rsum += acc[0] * aw.x + acc[1] * aw.y + acc[2] * aw.z + acc[3] * aw.w;
    }
  }
  if (wave == 3) {   // wave 3 owned both root tiles -> full r_dot
    rsum += __shfl_xor(rsum, 16);
    rsum += __shfl_xor(rsum, 32);
    if (lane < 16) od[node].y = __float_as_uint(rsum);
  }
  __syncthreads();
  // copy-out: 1600 uint4 (16B) stores — node nd row = 100 uint4; each
  // thread fuses the two 8B LDS slots (2*t2, 2*t2+1) into one 16B store.
  uint4* dst4 = reinterpret_cast<uint4*>(xw) + (size_t)n0 * 100;
  for (int j = tid; j < 1600; j += 256) {
    int nd = j / 100;
    int t2 = (j - nd * 100) * 2;
    uint2 lo = st[t2 * 16 + (nd ^ (t2 & 15))];
    uint2 hi = st[(t2 + 1) * 16 + (nd ^ ((t2 + 1) & 15))];
    uint4 v;
    v.x = lo.x; v.y = lo.y; v.z = hi.x; v.w = hi.y;
    dst4[j] = v;
  }
  rank[e] = (unsigned short)rk;
}

// ---------------------------------------------------------------------------
// 3-kernel exclusive scan of deg -> offs.
// ---------------------------------------------------------------------------
__global__ __launch_bounds__(256) void kscan1(const int* __restrict__ deg,
                                              int* __restrict__ incl,
                                              int* __restrict__ bsum) {
  __shared__ int s[256];
  int tid = threadIdx.x;
  int i = blockIdx.x * 256 + tid;
  int v = (i < N_NODES) ? deg[i] : 0;
  s[tid] = v;
  __syncthreads();
  for (int d = 1; d < 256; d <<= 1) {
    int t = (tid >= d) ? s[tid - d] : 0;
    __syncthreads();
    s[tid] += t;
    __syncthreads();
  }
  if (i < N_NODES) incl[i] = s[tid];
  if (tid == 255) bsum[blockIdx.x] = s[255];
}

__global__ __launch_bounds__(512) void kscan2(const int* __restrict__ bsum,
                                              int* __restrict__ bbase) {
  __shared__ int s[512];
  int tid = threadIdx.x;
  int v = (tid < NBLK_SCAN) ? bsum[tid] : 0;
  s[tid] = v;
  __syncthreads();
  for (int d = 1; d < 512; d <<= 1) {
    int t = (tid >= d) ? s[tid - d] : 0;
    __syncthreads();
    s[tid] += t;
    __syncthreads();
  }
  if (tid < NBLK_SCAN) bbase[tid] = s[tid] - v;  // exclusive
}

__global__ __launch_bounds__(256) void kscan3(const int* __restrict__ deg,
                                              int* __restrict__ offs,
                                              const int* __restrict__ bbase,
                                              uint2* __restrict__ od) {
  int i = blockIdx.x * 256 + threadIdx.x;
  if (i < N_NODES) {
    int v = offs[i] - deg[i] + bbase[i >> 8];
    offs[i] = v;
    od[i].x = (unsigned int)v;   // pack exclusive offset next to r_dot bits
  }
  if (i == 0) {
    offs[N_NODES] = N_EDGES;
    od[N_NODES].x = (unsigned int)N_EDGES;   // k2 reads od[node+1].x
  }
}

// ---------------------------------------------------------------------------
// K_scatter: 1 edge/thread, 6250 blocks — pos = offs[row] + rank[e]
// (deterministic). ONE 8B packet per edge:
//   epack.x = col*800 + w0*32  (direct xw element offset; w0 = i0+5*i1 <= 18,
//             so max offset 79,999,999 < 80M — no pad row needed.
//             w1 = +32, w2 = +160, w3 = +192 in elements.)
//   epack.y = fr0_q16 | fr1_q16<<16
// ---------------------------------------------------------------------------
__global__ __launch_bounds__(256) void kscatter(
    const int* __restrict__ ei, const float* __restrict__ pseudo,
    const uint2* __restrict__ od, const unsigned short* __restrict__ rank,
    uint2* __restrict__ epack) {
  int e = blockIdx.x * 256 + threadIdx.x;
  int r = ei[e];
  int c = ei[N_EDGES + e];
  float p0 = pseudo[2 * e] * 4.f;
  float p1 = pseudo[2 * e + 1] * 4.f;
  int rk = rank[e];
  unsigned int offr = od[r].x;      // one random 8B line (800KB, L2-friendly)
  float fl0 = floorf(p0), fl1 = floorf(p1);
  float fr0 = p0 - fl0, fr1 = p1 - fl1;
  int i0 = (int)fl0, i1 = (int)fl1;
  int w0 = i0 + 5 * i1;
  unsigned int q0 = (unsigned int)(fr0 * 65535.f + 0.5f);
  unsigned int q1 = (unsigned int)(fr1 * 65535.f + 0.5f);
  uint2 pk;
  pk.x = (unsigned int)(c * 800 + w0 * 32);
  pk.y = q0 | (q1 << 16);
  epack[offr + rk] = pk;
}

// ---------------------------------------------------------------------------
// K2: one wave per node; halves process alternate edges (lane=f_out);
// 4-deep unroll per half. alpha inline: msg from 4 xw gathers at
// base[0],[32],[160],[192] (offset precomputed in epack.x — zero decode
// arithmetic), t = msg.att2 via 5-step shfl_xor reduce, leaky-relu + exp,
// acc += msg*ex, den += ex. Reads {offs, r_dot} from packed od.
// ---------------------------------------------------------------------------
__global__ __launch_bounds__(256) void k2_csr(
    const uint2* __restrict__ od, const uint2* __restrict__ epack,
    const unsigned short* __restrict__ xw, const float* __restrict__ att_w,
    float* __restrict__ out) {
  int tid = threadIdx.x;
  int wave = tid >> 6, lane = tid & 63;
  int node = blockIdx.x * 4 + wave;
  if (node >= N_NODES) return;
  int f = lane & 31, half = lane >> 5;
  uint2 v0 = od[node];
  int s0 = (int)v0.x;
  int s1 = (int)od[node + 1].x;
  float rd = __uint_as_float(v0.y);
  float a2 = att_w[32 + f];
  const unsigned short* xwf = xw + f;
  float acc = 0.f, den = 0.f;
  int i = s0 + half;
  const float Q = 1.f / 65535.f;

  for (; i + 6 < s1; i += 8) {
    uint2 p[4];
    p[0] = epack[i];     p[1] = epack[i + 2];
    p[2] = epack[i + 4]; p[3] = epack[i + 6];
    float fr0[4], fr1[4];
#pragma unroll
    for (int u = 0; u < 4; u++) {
      fr0[u] = (float)(p[u].y & 0xffff) * Q;
      fr1[u] = (float)(p[u].y >> 16) * Q;
    }
    float g0[4], g1[4], g2[4], g3[4];
#pragma unroll
    for (int u = 0; u < 4; u++) {
      const unsigned short* base = xwf + p[u].x;
      g0[u] = bf16_to_f32(base[0]);
      g1[u] = bf16_to_f32(base[32]);
      g2[u] = bf16_to_f32(base[160]);
      g3[u] = bf16_to_f32(base[192]);
    }
    float msg[4], t[4];
#pragma unroll
    for (int u = 0; u < 4; u++) {
      float c0 = 1.f - fr0[u], c1 = 1.f - fr1[u];
      msg[u] = c1 * (c0 * g0[u] + fr0[u] * g1[u]) +
               fr1[u] * (c0 * g2[u] + fr0[u] * g3[u]);
      t[u] = msg[u] * a2;
    }
#pragma unroll
    for (int m = 16; m >= 1; m >>= 1) {
      t[0] += __shfl_xor(t[0], m);
      t[1] += __shfl_xor(t[1], m);
      t[2] += __shfl_xor(t[2], m);
      t[3] += __shfl_xor(t[3], m);
    }
#pragma unroll
    for (int u = 0; u < 4; u++) {
      float alpha = rd + t[u];
      alpha = alpha > 0.f ? alpha : 0.2f * alpha;
      float ex = __expf(alpha);
      acc += msg[u] * ex;
      den += ex;
    }
  }
  for (; i < s1; i += 2) {
    uint2 pv = epack[i];
    float fr0 = (float)(pv.y & 0xffff) * Q;
    float fr1 = (float)(pv.y >> 16) * Q;
    const unsigned short* base = xwf + pv.x;
    float g0 = bf16_to_f32(base[0]);
    float g1 = bf16_to_f32(base[32]);
    float g2 = bf16_to_f32(base[160]);
    float g3 = bf16_to_f32(base[192]);
    float c0 = 1.f - fr0, c1 = 1.f - fr1;
    float msg = c1 * (c0 * g0 + fr0 * g1) + fr1 * (c0 * g2 + fr0 * g3);
    float t = msg * a2;
#pragma unroll
    for (int m = 16; m >= 1; m >>= 1) t += __shfl_xor(t, m);
    float alpha = rd + t;
    alpha = alpha > 0.f ? alpha : 0.2f * alpha;
    float ex = __expf(alpha);
    acc += msg * ex;
    den += ex;
  }

  acc += __shfl_xor(acc, 32);
  den += __shfl_xor(den, 32);
  if (half == 0) out[node * 32 + f] += acc / (den + 1e-16f);
}

extern "C" void kernel_launch(void* const* d_in, const int* in_sizes, int n_in,
                              void* d_out, int out_size, void* d_ws, size_t ws_size,
                              hipStream_t stream) {
  const float* x      = (const float*)d_in[0];
  const int*   ei     = (const int*)d_in[1];
  const float* pseudo = (const float*)d_in[2];
  const float* weight = (const float*)d_in[3];
  const float* root_w = (const float*)d_in[4];
  const float* att_w  = (const float*)d_in[5];
  const float* bias   = (const float*)d_in[6];
  float* out = (float*)d_out;

  char* ws = (char*)d_ws;
  unsigned short* xw   = (unsigned short*)ws;                 // 160,000,000 B
  uint2* od            = (uint2*)(ws + 160000000);            //     800,016 B {offs, r_dot} x (N+1)
  unsigned short* wbf  = (unsigned short*)(ws + 160800016);   //      53,248 B (52 tiles)
  int* deg             = (int*)(ws + 160853264);              //     400,000 B
  int* offs            = (int*)(ws + 161253264);              //     400,016 B
  int* bsum            = (int*)(ws + 161653280);              //       1,600 B
  int* bbase           = (int*)(ws + 161654880);              //       1,600 B
  unsigned short* rank = (unsigned short*)(ws + 161656480);   //   3,200,000 B
  uint2* epack         = (uint2*)(ws + 164856480);            //  12,800,000 B -> 177.66 MB

  hipLaunchKernelGGL(k_zero, dim3(NBLK_SCAN), dim3(256), 0, stream,
                     weight, root_w, deg, wbf);
  hipLaunchKernelGGL(k1_xw, dim3(6250), dim3(256), 0, stream,
                     x, wbf, ei, att_w, bias, deg, rank, xw, out, od);
  hipLaunchKernelGGL(kscan1, dim3(NBLK_SCAN), dim3(256), 0, stream, deg, offs, bsum);
  hipLaunchKernelGGL(kscan2, dim3(1), dim3(512), 0, stream, bsum, bbase);
  hipLaunchKernelGGL(kscan3, dim3(NBLK_SCAN), dim3(256), 0, stream,
                     deg, offs, bbase, od);
  hipLaunchKernelGGL(kscatter, dim3(6250), dim3(256), 0, stream,
                     ei, pseudo, od, rank, epack);
  hipLaunchKernelGGL(k2_csr, dim3(25000), dim3(256), 0, stream,
                     od, epack, xw, att_w, out);
}

// Round 14
// 327.962 us; speedup vs baseline: 1.3121x; 1.0045x over previous
//
#include <hip/hip_runtime.h>
#include <stdint.h>

#define N_NODES 100000
#define N_EDGES 1600000
#define NBLK_SCAN 391   // ceil(N_NODES/256)

typedef __attribute__((ext_vector_type(8))) short short8;
typedef __attribute__((ext_vector_type(4))) float float4v;

__device__ __forceinline__ unsigned short f32_to_bf16(float f) {
  uint32_t u = __float_as_uint(f);
  u += 0x7fffu + ((u >> 16) & 1u);   // RNE
  return (unsigned short)(u >> 16);
}
__device__ __forceinline__ float bf16_to_f32(unsigned short h) {
  return __uint_as_float(((uint32_t)h) << 16);
}

// ---------------------------------------------------------------------------
// K_zero: deg=0, done=0; build wbf = 52 MFMA A-fragment tiles (A = W^T):
//   tiles 0..49 : A[row=fo_local][k=fin] = weight[km=t>>1][fin][(t&1)*16+row]
//   tiles 50,51 : root_w^T
// slot((t,q,row,j)) = t*512 + q*128 + row*8 + j,  fin = q*8+j.
// ---------------------------------------------------------------------------
__global__ __launch_bounds__(256) void k_zero(
    const float* __restrict__ weight, const float* __restrict__ root_w,
    int* __restrict__ deg, unsigned short* __restrict__ wbf,
    int* __restrict__ done) {
  int tid = threadIdx.x;
  int b = blockIdx.x;
  int i = b * 256 + tid;
  if (i < N_NODES) deg[i] = 0;
  if (b < 100) {            // 25600 weight-tile slots
    int e = i;
    int t = e >> 9, rem = e & 511;
    int q = rem >> 7, row = (rem >> 3) & 15, j = rem & 7;
    int km = t >> 1, fin = q * 8 + j, fo = (t & 1) * 16 + row;
    wbf[e] = f32_to_bf16(weight[(km * 32 + fin) * 32 + fo]);
  } else if (b == 100) {    // root tiles 50,51
    for (int idx = tid; idx < 1024; idx += 256) {
      int t = 50 + (idx >> 9), rem = idx & 511;
      int q = rem >> 7, row = (rem >> 3) & 15, j = rem & 7;
      int fin = q * 8 + j, fo = (t - 50) * 16 + row;
      wbf[t * 512 + rem] = f32_to_bf16(root_w[fin * 32 + fo]);
    }
  } else if (b == 101) {
    if (tid == 0) done[0] = 0;   // last-block counter for kscan1m
  }
}

// ---------------------------------------------------------------------------
// K1 (6250 blocks, 16 nodes each) — round-10 structure exactly (best: 322us;
// round-13's uint4 copy-out regressed: conflicts 600K->1.7M, 106->113us).
//  - hist: rank[e] = atomicAdd(&deg[ei[e]],1), stored at the end.
//  - 52 tiles = 4 waves x 13: uniform loop.
//  - D[fo][node]: lane packs 4 features of one node as uint2, staged at
//    swizzled LDS slot tq*16 + (c16 ^ (tq&15)); copy-out is 25.6 KB of
//    linear global per block (512 B per wave-instr, uint2 stores).
//  - tiles 50,51 (wave 3): out = x_root + bias; r_dot[node] (own array now).
// ---------------------------------------------------------------------------
__global__ __launch_bounds__(256) void k1_xw(
    const float* __restrict__ x, const unsigned short* __restrict__ wbf,
    const int* __restrict__ ei, const float* __restrict__ att_w,
    const float* __restrict__ bias,
    int* __restrict__ deg, unsigned short* __restrict__ rank,
    unsigned short* __restrict__ xw, float* __restrict__ out,
    float* __restrict__ r_dot) {
  __shared__ __align__(16) uint2 st[3200];   // 25.6 KB: tiles 0..49
  int tid = threadIdx.x;
  int b = blockIdx.x;

  int e = b * 256 + tid;
  int rk = atomicAdd(&deg[ei[e]], 1);

  int wave = tid >> 6, lane = tid & 63;
  int quad = lane >> 4, c16 = lane & 15;
  int n0 = b * 16;
  int node = n0 + c16;
  // B-fragment = x^T: lane holds x[node=c16][fin = quad*8 + j]
  const float* xp = x + (size_t)node * 32 + quad * 8;
  float4 a0 = *reinterpret_cast<const float4*>(xp);
  float4 a1 = *reinterpret_cast<const float4*>(xp + 4);
  short8 af;
  af[0] = (short)f32_to_bf16(a0.x); af[1] = (short)f32_to_bf16(a0.y);
  af[2] = (short)f32_to_bf16(a0.z); af[3] = (short)f32_to_bf16(a0.w);
  af[4] = (short)f32_to_bf16(a1.x); af[5] = (short)f32_to_bf16(a1.y);
  af[6] = (short)f32_to_bf16(a1.z); af[7] = (short)f32_to_bf16(a1.w);

  float rsum = 0.f;
  for (int idx = 0; idx < 13; idx++) {
    int t = wave * 13 + idx;
    short8 bf = *reinterpret_cast<const short8*>(wbf + ((t * 4 + quad) * 16 + c16) * 8);
    float4v acc = {0.f, 0.f, 0.f, 0.f};
    acc = __builtin_amdgcn_mfma_f32_16x16x32_bf16(bf, af, acc, 0, 0, 0);
    // D: col=lane&15=node, row=quad*4+r = fo_local
    if (t < 50) {
      uint2 pk;
      pk.x = (unsigned int)f32_to_bf16(acc[0]) |
             ((unsigned int)f32_to_bf16(acc[1]) << 16);
      pk.y = (unsigned int)f32_to_bf16(acc[2]) |
             ((unsigned int)f32_to_bf16(acc[3]) << 16);
      int tq = t * 4 + quad;
      st[tq * 16 + (c16 ^ (tq & 15))] = pk;
    } else {               // wave 3 only: tiles 50,51
      int gfo = (t - 50) * 16 + quad * 4;
      float4 bi = *reinterpret_cast<const float4*>(bias + gfo);
      float4 o;
      o.x = acc[0] + bi.x; o.y = acc[1] + bi.y;
      o.z = acc[2] + bi.z; o.w = acc[3] + bi.w;
      *reinterpret_cast<float4*>(out + (size_t)node * 32 + gfo) = o;
      float4 aw = *reinterpret_cast<const float4*>(att_w + gfo);
      rsum += acc[0] * aw.x + acc[1] * aw.y + acc[2] * aw.z + acc[3] * aw.w;
    }
  }
  if (wave == 3) {   // wave 3 owned both root tiles -> full r_dot
    rsum += __shfl_xor(rsum, 16);
    rsum += __shfl_xor(rsum, 32);
    if (lane < 16) r_dot[node] = rsum;
  }
  __syncthreads();
  // copy-out: dst is 3200 CONSECUTIVE uint2 (block writes 25.6 KB linear)
  uint2* dst = reinterpret_cast<uint2*>(xw) + (size_t)n0 * 200;
  for (int j = tid; j < 3200; j += 256) {
    int nd = j / 200;
    int tq = j - nd * 200;
    dst[j] = st[tq * 16 + (nd ^ (tq & 15))];
  }
  rank[e] = (unsigned short)rk;
}

// ---------------------------------------------------------------------------
// kscan1m: merged scan (replaces kscan1+kscan2+kscan3 — launch gaps were
// ~10us each; 7->5 launches). Per block: block-local inclusive scan of deg,
// write id2[i] = {incl_local, deg}; write bsum[b]; last-arriving block
// (device atomic counter) scans the 391 bsums -> bbase (exclusive).
// Cross-XCD safety (Guideline 16): writers do __threadfence() (agent
// release) BEFORE atomicAdd(done); the last block reads bsum via
// device-scope atomic loads (bypasses non-coherent per-XCD L2).
// Consumers reconstruct: s0 = incl - deg + bbase[blk]; s1 = incl + bbase.
// ---------------------------------------------------------------------------
__global__ __launch_bounds__(256) void kscan1m(
    const int* __restrict__ deg, uint2* __restrict__ id2,
    int* __restrict__ bsum, int* __restrict__ bbase, int* __restrict__ done) {
  __shared__ int s[256];
  __shared__ int islast;
  int tid = threadIdx.x;
  int b = blockIdx.x;
  int i = b * 256 + tid;
  int v = (i < N_NODES) ? deg[i] : 0;
  s[tid] = v;
  __syncthreads();
  for (int d = 1; d < 256; d <<= 1) {
    int t = (tid >= d) ? s[tid - d] : 0;
    __syncthreads();
    s[tid] += t;
    __syncthreads();
  }
  if (i < N_NODES) {
    uint2 pk; pk.x = (unsigned int)s[tid]; pk.y = (unsigned int)v;
    id2[i] = pk;
  }
  if (tid == 255) bsum[b] = s[255];
  __syncthreads();
  if (tid == 0) {
    __threadfence();   // agent release: bsum visible at coherent point
    islast = (atomicAdd(done, 1) == NBLK_SCAN - 1);
  }
  __syncthreads();
  if (!islast) return;
  // last block: scan 391 bsums with 256 threads, 2 chunks
  int v0 = __hip_atomic_load(&bsum[tid], __ATOMIC_RELAXED,
                             __HIP_MEMORY_SCOPE_AGENT);
  s[tid] = v0;
  __syncthreads();
  for (int d = 1; d < 256; d <<= 1) {
    int t = (tid >= d) ? s[tid - d] : 0;
    __syncthreads();
    s[tid] += t;
    __syncthreads();
  }
  bbase[tid] = s[tid] - v0;
  int carry = s[255];
  __syncthreads();
  int v1 = (tid < NBLK_SCAN - 256)
               ? __hip_atomic_load(&bsum[256 + tid], __ATOMIC_RELAXED,
                                   __HIP_MEMORY_SCOPE_AGENT)
               : 0;
  s[tid] = v1;
  __syncthreads();
  for (int d = 1; d < 256; d <<= 1) {
    int t = (tid >= d) ? s[tid - d] : 0;
    __syncthreads();
    s[tid] += t;
    __syncthreads();
  }
  if (tid < NBLK_SCAN - 256) bbase[256 + tid] = carry + s[tid] - v1;
}

// ---------------------------------------------------------------------------
// K_scatter: 1 edge/thread, 6250 blocks — pos = (incl - deg + bbase) + rank.
// ONE 8B packet per edge:
//   epack.x = col*800 + w0*32  (direct xw element offset; w0 = i0+5*i1 <= 18,
//             max offset 79,999,999 < 80M. w1=+32, w2=+160, w3=+192 elems.)
//   epack.y = fr0_q16 | fr1_q16<<16
// ---------------------------------------------------------------------------
__global__ __launch_bounds__(256) void kscatter(
    const int* __restrict__ ei, const float* __restrict__ pseudo,
    const uint2* __restrict__ id2, const int* __restrict__ bbase,
    const unsigned short* __restrict__ rank, uint2* __restrict__ epack) {
  int e = blockIdx.x * 256 + threadIdx.x;
  int r = ei[e];
  int c = ei[N_EDGES + e];
  float p0 = pseudo[2 * e] * 4.f;
  float p1 = pseudo[2 * e + 1] * 4.f;
  int rk = rank[e];
  uint2 idv = id2[r];               // one random 8B line (800KB, L2-friendly)
  int pos = (int)idv.x - (int)idv.y + bbase[r >> 8] + rk;
  float fl0 = floorf(p0), fl1 = floorf(p1);
  float fr0 = p0 - fl0, fr1 = p1 - fl1;
  int i0 = (int)fl0, i1 = (int)fl1;
  int w0 = i0 + 5 * i1;
  unsigned int q0 = (unsigned int)(fr0 * 65535.f + 0.5f);
  unsigned int q1 = (unsigned int)(fr1 * 65535.f + 0.5f);
  uint2 pk;
  pk.x = (unsigned int)(c * 800 + w0 * 32);
  pk.y = q0 | (q1 << 16);
  epack[pos] = pk;
}

// ---------------------------------------------------------------------------
// K2: one wave per node; halves process alternate edges (lane=f_out);
// 4-deep unroll per half. alpha inline: msg from 4 xw gathers at
// base[0],[32],[160],[192] (offset precomputed in epack.x), t = msg.att2
// via 5-step shfl_xor reduce, leaky-relu + exp, acc += msg*ex, den += ex.
// Segment: s1 = incl + bbase; s0 = s1 - deg  (id2 + hot bbase, no sentinel).
// ---------------------------------------------------------------------------
__global__ __launch_bounds__(256) void k2_csr(
    const uint2* __restrict__ id2, const int* __restrict__ bbase,
    const float* __restrict__ r_dot, const uint2* __restrict__ epack,
    const unsigned short* __restrict__ xw, const float* __restrict__ att_w,
    float* __restrict__ out) {
  int tid = threadIdx.x;
  int wave = tid >> 6, lane = tid & 63;
  int node = blockIdx.x * 4 + wave;
  if (node >= N_NODES) return;
  int f = lane & 31, half = lane >> 5;
  uint2 v0 = id2[node];
  int s1 = (int)v0.x + bbase[node >> 8];
  int s0 = s1 - (int)v0.y;
  float rd = r_dot[node];
  float a2 = att_w[32 + f];
  const unsigned short* xwf = xw + f;
  float acc = 0.f, den = 0.f;
  int i = s0 + half;
  const float Q = 1.f / 65535.f;

  for (; i + 6 < s1; i += 8) {
    uint2 p[4];
    p[0] = epack[i];     p[1] = epack[i + 2];
    p[2] = epack[i + 4]; p[3] = epack[i + 6];
    float fr0[4], fr1[4];
#pragma unroll
    for (int u = 0; u < 4; u++) {
      fr0[u] = (float)(p[u].y & 0xffff) * Q;
      fr1[u] = (float)(p[u].y >> 16) * Q;
    }
    float g0[4], g1[4], g2[4], g3[4];
#pragma unroll
    for (int u = 0; u < 4; u++) {
      const unsigned short* base = xwf + p[u].x;
      g0[u] = bf16_to_f32(base[0]);
      g1[u] = bf16_to_f32(base[32]);
      g2[u] = bf16_to_f32(base[160]);
      g3[u] = bf16_to_f32(base[192]);
    }
    float msg[4], t[4];
#pragma unroll
    for (int u = 0; u < 4; u++) {
      float c0 = 1.f - fr0[u], c1 = 1.f - fr1[u];
      msg[u] = c1 * (c0 * g0[u] + fr0[u] * g1[u]) +
               fr1[u] * (c0 * g2[u] + fr0[u] * g3[u]);
      t[u] = msg[u] * a2;
    }
#pragma unroll
    for (int m = 16; m >= 1; m >>= 1) {
      t[0] += __shfl_xor(t[0], m);
      t[1] += __shfl_xor(t[1], m);
      t[2] += __shfl_xor(t[2], m);
      t[3] += __shfl_xor(t[3], m);
    }
#pragma unroll
    for (int u = 0; u < 4; u++) {
      float alpha = rd + t[u];
      alpha = alpha > 0.f ? alpha : 0.2f * alpha;
      float ex = __expf(alpha);
      acc += msg[u] * ex;
      den += ex;
    }
  }
  for (; i < s1; i += 2) {
    uint2 pv = epack[i];
    float fr0 = (float)(pv.y & 0xffff) * Q;
    float fr1 = (float)(pv.y >> 16) * Q;
    const unsigned short* base = xwf + pv.x;
    float g0 = bf16_to_f32(base[0]);
    float g1 = bf16_to_f32(base[32]);
    float g2 = bf16_to_f32(base[160]);
    float g3 = bf16_to_f32(base[192]);
    float c0 = 1.f - fr0, c1 = 1.f - fr1;
    float msg = c1 * (c0 * g0 + fr0 * g1) + fr1 * (c0 * g2 + fr0 * g3);
    float t = msg * a2;
#pragma unroll
    for (int m = 16; m >= 1; m >>= 1) t += __shfl_xor(t, m);
    float alpha = rd + t;
    alpha = alpha > 0.f ? alpha : 0.2f * alpha;
    float ex = __expf(alpha);
    acc += msg * ex;
    den += ex;
  }

  acc += __shfl_xor(acc, 32);
  den += __shfl_xor(den, 32);
  if (half == 0) out[node * 32 + f] += acc / (den + 1e-16f);
}

extern "C" void kernel_launch(void* const* d_in, const int* in_sizes, int n_in,
                              void* d_out, int out_size, void* d_ws, size_t ws_size,
                              hipStream_t stream) {
  const float* x      = (const float*)d_in[0];
  const int*   ei     = (const int*)d_in[1];
  const float* pseudo = (const float*)d_in[2];
  const float* weight = (const float*)d_in[3];
  const float* root_w = (const float*)d_in[4];
  const float* att_w  = (const float*)d_in[5];
  const float* bias   = (const float*)d_in[6];
  float* out = (float*)d_out;

  char* ws = (char*)d_ws;
  unsigned short* xw   = (unsigned short*)ws;                 // 160,000,000 B
  float* r_dot         = (float*)(ws + 160000000);            //     400,000 B
  unsigned short* wbf  = (unsigned short*)(ws + 160400000);   //      53,248 B (52 tiles)
  int* deg             = (int*)(ws + 160453248);              //     400,000 B
  uint2* id2           = (uint2*)(ws + 160853248);            //     800,000 B {incl, deg}
  int* bsum            = (int*)(ws + 161653248);              //       1,600 B
  int* bbase           = (int*)(ws + 161654848);              //       1,600 B
  int* done            = (int*)(ws + 161656448);              //          16 B
  unsigned short* rank = (unsigned short*)(ws + 161656464);   //   3,200,000 B
  uint2* epack         = (uint2*)(ws + 164856464);            //  12,800,000 B -> 177.66 MB

  hipLaunchKernelGGL(k_zero, dim3(NBLK_SCAN), dim3(256), 0, stream,
                     weight, root_w, deg, wbf, done);
  hipLaunchKernelGGL(k1_xw, dim3(6250), dim3(256), 0, stream,
                     x, wbf, ei, att_w, bias, deg, rank, xw, out, r_dot);
  hipLaunchKernelGGL(kscan1m, dim3(NBLK_SCAN), dim3(256), 0, stream,
                     deg, id2, bsum, bbase, done);
  hipLaunchKernelGGL(kscatter, dim3(6250), dim3(256), 0, stream,
                     ei, pseudo, id2, bbase, rank, epack);
  hipLaunchKernelGGL(k2_csr, dim3(25000), dim3(256), 0, stream,
                     id2, bbase, r_dot, epack, xw, att_w, out);
}